// Round 15
// baseline (1415.808 us; speedup 1.0000x reference)
//
#include <hip/hip_runtime.h>
#include <hip/hip_bf16.h>
#include <math.h>

#define NEGF (-1000000000.0f)

constexpr int Bc = 8;
constexpr int Sc = 64;
constexpr int Hc = 512;
constexpr int Tc = 17;
constexpr int TRIc = Sc*(Sc+1)/2;     // 2080
constexpr int PTN  = Bc*Tc*Sc*Sc;     // elements per pt part

typedef __bf16 bf16x8 __attribute__((ext_vector_type(8)));
typedef float  f32x4  __attribute__((ext_vector_type(4)));

__device__ __forceinline__ int tri_idx(int i, int j){
  return i*Sc - (i*(i-1))/2 + (j - i);
}

__device__ __forceinline__ float bfu(ushort s){
  union { ushort u; __hip_bfloat16 h; } x; x.u = s;
  return __bfloat162float(x.h);
}

// (i,j) position + activity for (pass, row r, step k, length L)
__device__ __forceinline__ void posmap(int pass, int r, int k, int L,
                                       int& i, int& j, bool& act){
  if      (pass == 0){ act = (r < L - k);            i = r;     j = L - 1 - k; }
  else if (pass == 1){ act = (r < L - k);            i = r;     j = r + k;     }
  else if (pass == 2){ act = (r >= k) && (r < L);    i = r - k; j = r;         }
  else               { act = (r >= k) && (r < L);    i = k;     j = r;         }
  if (!act){ i = 0; j = 0; }
}

// masked pt value; pt split in 4 parts of PTN elements
__device__ __forceinline__ float pt_val(const float* __restrict__ pt_acc,
                                        const float* __restrict__ btv,
                                        int b, int t, int i, int j, int L){
  const bool masked = (i > j) || (j >= L) ||
                      (t < Tc-1 && i == j) || (t == Tc-1 && i < j);
  if (masked) return NEGF;
  const size_t idx = (((size_t)b*Tc + t)*Sc + i)*Sc + j;
  return pt_acc[idx] + pt_acc[PTN + idx] + pt_acc[2*PTN + idx]
       + pt_acc[3*PTN + idx] + btv[t];
}

// ---------------------------------------------------------------------------
__global__ __launch_bounds__(256) void k_cvt(const float* __restrict__ s,
                                             __hip_bfloat16* __restrict__ d, int n4){
  int i = blockIdx.x*256 + threadIdx.x;
  if (i >= n4) return;
  float4 v = reinterpret_cast<const float4*>(s)[i];
  union { __hip_bfloat16 h[4]; ushort4 u; } p;
  p.h[0] = __float2bfloat16(v.x); p.h[1] = __float2bfloat16(v.y);
  p.h[2] = __float2bfloat16(v.z); p.h[3] = __float2bfloat16(v.w);
  reinterpret_cast<ushort4*>(d)[i] = p.u;
}

// ---------------------------------------------------------------------------
// Weight prepack: Wp[wset][us(32)][row(64)][k(1024)] bf16
//   row = g*16 + uu <-> source row g*512 + us*16 + uu
//   k < 512 -> Whh[srow][k] ; k >= 512 -> Wih[srow][k-512]
// ---------------------------------------------------------------------------
__global__ __launch_bounds__(256) void k_pack(
    const float* __restrict__ Whh_f, const float* __restrict__ Wih_f,
    const float* __restrict__ Whh_b, const float* __restrict__ Wih_b,
    __hip_bfloat16* __restrict__ Wp)
{
  int idx = blockIdx.x*256 + threadIdx.x;   // 1,048,576 quads
  int k4  = idx & 255;
  int row = (idx >> 8) & 63;
  int us  = (idx >> 14) & 31;
  int ws  = idx >> 19;
  int g = row >> 4, uu = row & 15;
  int srow = g*512 + us*16 + uu;
  int k = k4*4;
  const float* src;
  if (ws == 0) src = (k < 512) ? Whh_f : Wih_f;
  else         src = (k < 512) ? Whh_b : Wih_b;
  float4 v = *reinterpret_cast<const float4*>(src + (size_t)srow*512 + (k & 511));
  union { __hip_bfloat16 h[4]; ushort4 u; } p;
  p.h[0] = __float2bfloat16(v.x); p.h[1] = __float2bfloat16(v.y);
  p.h[2] = __float2bfloat16(v.z); p.h[3] = __float2bfloat16(v.w);
  *reinterpret_cast<ushort4*>(Wp + (size_t)idx*4) = p.u;
}

// ---------------------------------------------------------------------------
// G precompute: G[ws][us][row(16640)][uu*4+g] = Wih_ws . x[row] at gate-col
// g*512+us*16+uu. One-shot MFMA GEMM: grid (130, 32, 2), 512 threads,
// block tile 128 rows x 64 gate-cols, K=512. 64 KB LDS (Wih slice).
// ---------------------------------------------------------------------------
__global__ __launch_bounds__(512) void k_gemm_G(
    const __hip_bfloat16* __restrict__ Wp,
    const __hip_bfloat16* __restrict__ svb,
    __hip_bfloat16* __restrict__ G)
{
  const int m0 = blockIdx.x * 128;
  const int us = blockIdx.y;
  const int ws = blockIdx.z;
  const int t = threadIdx.x, lane = t & 63, wv = t >> 6;
  const int c15 = lane & 15, qq = lane >> 4;

  __shared__ ushort Wlds[32768];    // 64 KB: 64 rows x 1024 B, XOR-swizzled

  {
    const __hip_bfloat16* Wpb = Wp + (((size_t)ws*32 + us)*64)*1024 + 512;
    const int row = t >> 3, c8 = t & 7;
    const int swz = (row & 7) << 4;
    #pragma unroll
    for (int q=0; q<8; ++q){
      int4 v = *reinterpret_cast<const int4*>(Wpb + (size_t)row*1024 + c8*64 + q*8);
      *reinterpret_cast<int4*>((char*)Wlds + ((row*1024 + c8*128 + q*16) ^ swz)) = v;
    }
  }
  __syncthreads();
  const int lswz = (c15 & 7) << 4;

  const int arow = m0 + wv*16 + c15;
  const __hip_bfloat16* xp = svb + (size_t)arow*512;

  f32x4 acc[4];
  #pragma unroll
  for (int g=0; g<4; ++g) acc[g] = f32x4{0.f,0.f,0.f,0.f};

  #pragma unroll
  for (int c=0; c<8; ++c){
    const int o = c*64 + qq*8;
    bf16x8 a0 = *reinterpret_cast<const bf16x8*>(xp + o);
    bf16x8 a1 = *reinterpret_cast<const bf16x8*>(xp + o + 32);
    #pragma unroll
    for (int g=0; g<4; ++g){
      const int ad0 = (((g*16 + c15)*1024) + (c*2+0)*64 + qq*16) ^ lswz;
      const int ad1 = (((g*16 + c15)*1024) + (c*2+1)*64 + qq*16) ^ lswz;
      acc[g] = __builtin_amdgcn_mfma_f32_16x16x32_bf16(
          a0, *reinterpret_cast<const bf16x8*>((const char*)Wlds + ad0), acc[g], 0,0,0);
      acc[g] = __builtin_amdgcn_mfma_f32_16x16x32_bf16(
          a1, *reinterpret_cast<const bf16x8*>((const char*)Wlds + ad1), acc[g], 0,0,0);
    }
  }

  __hip_bfloat16* Gb = G + ((size_t)ws*32 + us)*16640*64;
  #pragma unroll
  for (int e=0; e<4; ++e){
    const int row = m0 + wv*16 + qq*4 + e;
    union { __hip_bfloat16 h[4]; ushort4 u; } pk;
    pk.h[0] = __float2bfloat16(acc[0][e]);
    pk.h[1] = __float2bfloat16(acc[1][e]);
    pk.h[2] = __float2bfloat16(acc[2][e]);
    pk.h[3] = __float2bfloat16(acc[3][e]);
    *reinterpret_cast<ushort4*>(Gb + (size_t)row*64 + c15*4) = pk.u;
  }
}

// ---------------------------------------------------------------------------
// Persistent 4-pass LSTM, G-fed. 256 blocks x 512 threads, 1 block/CU.
// grp = bid&7 (XCD-pinned: pp = grp>>2 weight set, bq = grp&3 batch pair);
// us = bid>>3. K-loop now h-only (K=512, Whh in 64 KB LDS); x contribution
// read from per-block G slice (8 B/row, no cross-block duplication).
// All 32 h-loads issued upfront (static indices) for deep latency hiding.
// Sync: R14-proven (plain-store slots, coalesced poll, buffer_inv sc0).
// ---------------------------------------------------------------------------
__global__ __launch_bounds__(512) void k_persist(
    const __hip_bfloat16* __restrict__ Wp,
    const float* __restrict__ bih_f, const float* __restrict__ bhh_f,
    const float* __restrict__ bih_b, const float* __restrict__ bhh_b,
    const __hip_bfloat16* __restrict__ G, const float* __restrict__ Wt,
    const int* __restrict__ lens,
    __hip_bfloat16* __restrict__ H,
    float* __restrict__ pt_acc, int* __restrict__ flags)
{
  const int bid = blockIdx.x;
  const int grp = bid & 7;          // XCD-aligned group
  const int us  = bid >> 3;         // 0..31
  const int pp  = grp >> 2;         // weight set (one per XCD)
  const int bq  = grp & 3;          // batch pair (one per XCD)
  const int L0 = lens[bq*2], L1 = lens[bq*2+1];
  const int kmax = (L0 > L1) ? L0 : L1;

  const float* b1 = pp ? bih_b : bih_f;
  const float* b2 = pp ? bhh_b : bhh_f;

  const int t = threadIdx.x, lane = t & 63, wv = t >> 6;
  const int c15 = lane & 15, qq = lane >> 4;
  const int ph = wv >> 2;           // pass half
  const int mq = wv & 3;            // row quarter
  const int pass = pp ? (ph ? 2 : 1) : (ph ? 3 : 0);
  const int b_loc = mq >> 1;
  const int b  = bq*2 + b_loc;
  const int L  = b_loc ? L1 : L0;
  const int rb0 = (mq & 1)*32;      // within-batch row base (+mt*16)

  __shared__ ushort Wlds[32768];    // 64 KB: Whh slice, 64 rows x 1024 B

  {
    const __hip_bfloat16* Wpb = Wp + (((size_t)pp*32 + us)*64)*1024;
    const int row = t >> 3, c8 = t & 7;
    const int swz = (row & 7) << 4;
    #pragma unroll
    for (int q=0; q<8; ++q){
      int4 v = *reinterpret_cast<const int4*>(Wpb + (size_t)row*1024 + c8*64 + q*8);
      *reinterpret_cast<int4*>((char*)Wlds + ((row*1024 + c8*128 + q*16) ^ swz)) = v;
    }
  }

  const int u = us*16 + c15;
  const float bsI = b1[u]        + b2[u];
  const float bsF = b1[512 + u]  + b2[512 + u];
  const float bsG = b1[1024 + u] + b2[1024 + u];
  const float bsO = b1[1536 + u] + b2[1536 + u];
  const int lswz = (c15 & 7) << 4;

  const __hip_bfloat16* Gb = G + ((size_t)pp*32 + us)*16640*64;

  // sync slots for this group (32 ints, monotonic step counters)
  int* slots = flags + grp*32;

  // projection: pidx = us*4 + mq in 0..127 per pass-half (bijective over grp)
  const int pidx = us*4 + mq;
  const int bp   = bq*2 + (pidx >> 6);
  const int rp   = pidx & 63;
  const int Lp   = (pidx >> 6) ? L1 : L0;
  const int off_wtp = (pass==0 || pass==2) ? 512 : 0;

  float creg[2][4];
  #pragma unroll
  for (int mt=0; mt<2; ++mt)
    #pragma unroll
    for (int e=0; e<4; ++e) creg[mt][e] = 0.f;

  __syncthreads();                  // Wlds ready

  for (int k=0; k<kmax; ++k){
    const int cur = k & 1;

    bool act_t[2];
    #pragma unroll
    for (int mt=0; mt<2; ++mt){
      const int rbase = rb0 + mt*16;
      act_t[mt] = (pass < 2) ? (rbase < L - k)
                             : (rbase + 15 >= k && rbase < L);
    }

    if (act_t[0] || act_t[1]){
      const __hip_bfloat16* hp[2];
      #pragma unroll
      for (int mt=0; mt<2; ++mt)
        hp[mt] = H + (((size_t)cur*4 + pass)*512 + b*64 + rb0 + mt*16 + c15)*512;

      // issue ALL h loads upfront (32 x b128) for deep latency hiding
      bf16x8 av[8][2][2];             // [c][kk][mt], static indices
      #pragma unroll
      for (int c=0; c<8; ++c){
        const int o = c*64 + qq*8;
        #pragma unroll
        for (int mt=0; mt<2; ++mt){
          av[c][0][mt] = *reinterpret_cast<const bf16x8*>(hp[mt] + o);
          av[c][1][mt] = *reinterpret_cast<const bf16x8*>(hp[mt] + o + 32);
        }
      }

      f32x4 acc[2][4];
      #pragma unroll
      for (int mt=0; mt<2; ++mt)
        #pragma unroll
        for (int g=0; g<4; ++g) acc[mt][g] = f32x4{0.f,0.f,0.f,0.f};

      #pragma unroll
      for (int c=0; c<8; ++c){
        #pragma unroll
        for (int kk=0; kk<2; ++kk){
          #pragma unroll
          for (int g=0; g<4; ++g){
            const int addr = (((g*16 + c15)*1024) + (c*2 + kk)*64 + qq*16) ^ lswz;
            bf16x8 bf = *reinterpret_cast<const bf16x8*>((const char*)Wlds + addr);
            acc[0][g] = __builtin_amdgcn_mfma_f32_16x16x32_bf16(av[c][kk][0], bf, acc[0][g], 0,0,0);
            acc[1][g] = __builtin_amdgcn_mfma_f32_16x16x32_bf16(av[c][kk][1], bf, acc[1][g], 0,0,0);
          }
        }
      }

      // cell epilogue: D row = rb0 + mt*16 + qq*4 + e, col = c15; + G + biases
      #pragma unroll
      for (int mt=0; mt<2; ++mt){
        #pragma unroll
        for (int e=0; e<4; ++e){
          const int r = rb0 + mt*16 + qq*4 + e;
          int i, j; bool act;
          posmap(pass, r, k, L, i, j, act);
          if (act){
            const size_t grow = (size_t)b*TRIc + tri_idx(i, j);
            const ushort4 gu = *reinterpret_cast<const ushort4*>(Gb + grow*64 + c15*4);
            float gi = acc[mt][0][e] + bsI + bfu(gu.x);
            float gf = acc[mt][1][e] + bsF + bfu(gu.y);
            float gg = acc[mt][2][e] + bsG + bfu(gu.z);
            float go = acc[mt][3][e] + bsO + bfu(gu.w);
            float ii = 1.f/(1.f + expf(-gi));
            float ff = 1.f/(1.f + expf(-gf));
            float gt = tanhf(gg);
            float oo = 1.f/(1.f + expf(-go));
            float cn = ff*creg[mt][e] + ii*gt;
            creg[mt][e] = cn;
            float hv = oo*tanhf(cn);
            H[(((size_t)(cur^1)*4 + pass)*512 + b*64 + r)*512 + u] = __float2bfloat16(hv);
          }
        }
      }
    }

    // ---- group sync (R14-proven): barrier (vmcnt drain) -> plain-store post
    // -> coalesced 32-slot poll -> L1-only invalidate -> release barrier.
    __syncthreads();
    if (wv == 0){
      if (lane == 0)
        __hip_atomic_store(&slots[us], k + 1, __ATOMIC_RELAXED,
                           __HIP_MEMORY_SCOPE_AGENT);
      for (;;){
        int v = 0x7fffffff;
        if (lane < 32)
          v = __hip_atomic_load(&slots[lane], __ATOMIC_RELAXED,
                                __HIP_MEMORY_SCOPE_AGENT);
        if (__all(v >= k + 1)) break;
        __builtin_amdgcn_s_sleep(2);
      }
      asm volatile("buffer_inv sc0\n\ts_waitcnt vmcnt(0)" ::: "memory");
    }
    __syncthreads();

    // ---- fused projection for step k (h complete in parity cur^1) ----
    if (k < Lp){
      int pi, pj; bool pact;
      posmap(pass, rp, k, Lp, pi, pj, pact);
      if (pact){
        const __hip_bfloat16* hrow =
            H + (((size_t)(cur^1)*4 + pass)*512 + bp*64 + rp)*512;
        bf16x8 hv8 = *reinterpret_cast<const bf16x8*>(hrow + lane*8);
        float hf[8];
        #pragma unroll
        for (int e=0; e<8; ++e) hf[e] = (float)hv8[e];
        float part[Tc];
        #pragma unroll
        for (int tt=0; tt<Tc; ++tt){
          const float* w = Wt + (size_t)tt*1024 + off_wtp + lane*8;
          float4 w0 = *reinterpret_cast<const float4*>(w);
          float4 w1 = *reinterpret_cast<const float4*>(w + 4);
          part[tt] = hf[0]*w0.x + hf[1]*w0.y + hf[2]*w0.z + hf[3]*w0.w
                   + hf[4]*w1.x + hf[5]*w1.y + hf[6]*w1.z + hf[7]*w1.w;
        }
        float* ptp = pt_acc + (size_t)(us & 3)*PTN;
        #pragma unroll
        for (int tt=0; tt<Tc; ++tt){
          float s = part[tt];
          s += __shfl_xor(s, 1);  s += __shfl_xor(s, 2);  s += __shfl_xor(s, 4);
          s += __shfl_xor(s, 8);  s += __shfl_xor(s, 16); s += __shfl_xor(s, 32);
          if (lane == tt)
            atomicAdd(&ptp[(((size_t)bp*Tc + tt)*Sc + pi)*Sc + pj], s);
        }
      }
    }
  }
}

// labeled[b,i,j] = logsumexp_t of masked pt
__global__ void k_lse(const float* __restrict__ pt_acc, const float* __restrict__ btv,
                      const int* __restrict__ lens, float* __restrict__ lab){
  const int idx = blockIdx.x*256 + threadIdx.x;  // 32768
  const int b = idx >> 12, ij = idx & 4095;
  const int i = ij >> 6, j = ij & 63;
  const int L = lens[b];
  float vs[Tc]; float m = -INFINITY;
  #pragma unroll
  for (int t=0;t<Tc;t++){ vs[t] = pt_val(pt_acc, btv, b, t, i, j, L); m = fmaxf(m, vs[t]); }
  float ssum = 0.f;
  #pragma unroll
  for (int t=0;t<Tc;t++) ssum += expf(vs[t]-m);
  lab[idx] = m + logf(ssum);
}

// matrix-tree slogdet per batch; no-pivot LU (leading minors positive), double.
__global__ __launch_bounds__(256) void k_logz(
    const float* __restrict__ lab, const int* __restrict__ lens,
    float* __restrict__ out)
{
  __shared__ double Md[64][65];
  __shared__ double part[4][64];
  __shared__ double rootv[64];
  const int b = blockIdx.x;
  const int L = lens[b];
  const int tid = threadIdx.x;
  const int c  = tid & 63;
  const int rg = tid >> 6;

  for (int r = rg; r < 64; r += 4){
    float lv = lab[((size_t)b*Sc + r)*Sc + c];
    double a;
    if (r == c) a = 0.0;
    else { a = 1e-5; if (r < L && c < L) a += exp((double)lv); }
    Md[r][c] = a;
  }
  if (rg == 0) rootv[c] = (c < L) ? exp((double)lab[((size_t)b*Sc + c)*Sc + c]) : 0.0;
  __syncthreads();
  {
    double ps = 0.0;
    for (int r = rg; r < 64; r += 4) ps += Md[r][c];
    part[rg][c] = ps;
  }
  __syncthreads();
  const double cs = part[0][c] + part[1][c] + part[2][c] + part[3][c];
  for (int r = rg; r < 64; r += 4){
    double v;
    if (r == 0) v = rootv[c];
    else { v = -Md[r][c]; if (r == c) v += cs + ((c >= L) ? 1.0 : 0.0); }
    Md[r][c] = v;
  }
  __syncthreads();

  double logdet = 0.0;
  for (int p = 0; p < 64; ++p){
    const double diag = Md[p][p];
    logdet += log(fabs(diag));
    if (c > p){
      const double inv = 1.0/diag;
      const double mpc = Md[p][c];
      for (int r = p + 1 + rg; r < 64; r += 4)
        Md[r][c] -= Md[r][p]*inv*mpc;
    }
    __syncthreads();
  }
  if (tid == 0) out[(size_t)Bc*Tc*65*65 + b] = (float)logdet;
}

// pe = _expand_matrix(masked pt)
__global__ void k_out(const float* __restrict__ pt_acc, const float* __restrict__ btv,
                      const int* __restrict__ lens, float* __restrict__ out){
  const int idx = blockIdx.x*256 + threadIdx.x;
  if (idx >= Bc*Tc*65*65) return;
  const int cc = idx % 65; int tmp = idx / 65;
  const int rr = tmp % 65; tmp /= 65;
  const int t  = tmp % Tc; const int b = tmp / Tc;
  float v;
  if (rr == cc) v = 0.f;
  else if (cc == 0) v = NEGF;
  else {
    const int i = (rr == 0) ? (cc-1) : (rr-1);
    v = pt_val(pt_acc, btv, b, t, i, cc-1, lens[b]);
  }
  out[idx] = v;
}

__global__ void k_zero_out(float* out, int n){
  int i = blockIdx.x*256 + threadIdx.x;
  if (i < n) out[i] = 0.f;
}

// ---------------------------------------------------------------------------
extern "C" void kernel_launch(void* const* d_in, const int* in_sizes, int n_in,
                              void* d_out, int out_size, void* d_ws, size_t ws_size,
                              hipStream_t stream)
{
  (void)in_sizes; (void)n_in;
  const int*   lens  = (const int*)  d_in[2];
  const float* sv    = (const float*)d_in[3];
  const float* Wih_f = (const float*)d_in[5];
  const float* Whh_f = (const float*)d_in[6];
  const float* bih_f = (const float*)d_in[7];
  const float* bhh_f = (const float*)d_in[8];
  const float* Wih_b = (const float*)d_in[9];
  const float* Whh_b = (const float*)d_in[10];
  const float* bih_b = (const float*)d_in[11];
  const float* bhh_b = (const float*)d_in[12];
  const float* Wt    = (const float*)d_in[13];
  const float* btv   = (const float*)d_in[14];

  const size_t SVB  = (size_t)Bc*TRIc*Hc*2;       // 17.04 MB bf16
  const size_t WPB  = (size_t)2*32*64*1024*2;     // 8.39 MB bf16
  const size_t GB   = (size_t)2*32*16640*64*2;    // 136.3 MB bf16
  const size_t PT4  = (size_t)4*PTN*4;            // 8.92 MB (4 parts)
  const size_t HB   = (size_t)2*4*512*512*2;      // 4.19 MB bf16
  const size_t LAB  = (size_t)Bc*Sc*Sc*4;         // 131 KB
  const size_t FLG  = 1024;                       // 8 groups x 32 slots
  const size_t NEED = SVB + WPB + GB + PT4 + HB + LAB + FLG + 8192;

  if (ws_size < NEED) {
    k_zero_out<<<dim3((out_size+255)/256), 256, 0, stream>>>((float*)d_out, out_size);
    return;
  }

  char* base = (char*)d_ws;
  size_t off = 0;
  auto take = [&](size_t bytes)->char*{
    char* r = base + off; off += (bytes + 255) & ~(size_t)255; return r; };

  __hip_bfloat16* svb = (__hip_bfloat16*)take(SVB);
  __hip_bfloat16* Wp  = (__hip_bfloat16*)take(WPB);
  __hip_bfloat16* G   = (__hip_bfloat16*)take(GB);
  float* pt_acc = (float*)take(PT4);
  __hip_bfloat16* H = (__hip_bfloat16*)take(HB);
  float* lab = (float*)take(LAB);
  int*   flags = (int*)take(FLG);

  // zero pt parts + H + lab + flags (contiguous takes)
  (void)hipMemsetAsync(pt_acc, 0, PT4 + HB + LAB + FLG, stream);

  k_cvt  <<<dim3(8320), 256, 0, stream>>>(sv, svb, 2129920);
  k_pack <<<dim3(4096), 256, 0, stream>>>(Whh_f, Wih_f, Whh_b, Wih_b, Wp);
  k_gemm_G<<<dim3(130, 32, 2), 512, 0, stream>>>(Wp, svb, G);

  k_persist<<<dim3(256), 512, 0, stream>>>(Wp, bih_f, bhh_f, bih_b, bhh_b,
                                           G, Wt, lens, H, pt_acc, flags);

  k_lse <<<dim3(128), 256, 0, stream>>>(pt_acc, btv, lens, lab);
  k_logz<<<dim3(Bc), 256, 0, stream>>>(lab, lens, (float*)d_out);
  k_out <<<dim3((Bc*Tc*65*65 + 255)/256), 256, 0, stream>>>(pt_acc, btv, lens, (float*)d_out);
}

// Round 16
// 1085.658 us; speedup vs baseline: 1.3041x; 1.3041x over previous
//
#include <hip/hip_runtime.h>
#include <hip/hip_bf16.h>
#include <math.h>

#define NEGF (-1000000000.0f)

constexpr int Bc = 8;
constexpr int Sc = 64;
constexpr int Hc = 512;
constexpr int Tc = 17;
constexpr int TRIc = Sc*(Sc+1)/2;     // 2080
constexpr int PTN  = Bc*Tc*Sc*Sc;     // elements per pt part

typedef __bf16 bf16x8 __attribute__((ext_vector_type(8)));
typedef float  f32x4  __attribute__((ext_vector_type(4)));

__device__ __forceinline__ int tri_idx(int i, int j){
  return i*Sc - (i*(i-1))/2 + (j - i);
}

// (i,j) position + activity for (pass, row r, step k, length L)
__device__ __forceinline__ void posmap(int pass, int r, int k, int L,
                                       int& i, int& j, bool& act){
  if      (pass == 0){ act = (r < L - k);            i = r;     j = L - 1 - k; }
  else if (pass == 1){ act = (r < L - k);            i = r;     j = r + k;     }
  else if (pass == 2){ act = (r >= k) && (r < L);    i = r - k; j = r;         }
  else               { act = (r >= k) && (r < L);    i = k;     j = r;         }
  if (!act){ i = 0; j = 0; }
}

// masked pt value; pt split in 4 parts of PTN elements
__device__ __forceinline__ float pt_val(const float* __restrict__ pt_acc,
                                        const float* __restrict__ btv,
                                        int b, int t, int i, int j, int L){
  const bool masked = (i > j) || (j >= L) ||
                      (t < Tc-1 && i == j) || (t == Tc-1 && i < j);
  if (masked) return NEGF;
  const size_t idx = (((size_t)b*Tc + t)*Sc + i)*Sc + j;
  return pt_acc[idx] + pt_acc[PTN + idx] + pt_acc[2*PTN + idx]
       + pt_acc[3*PTN + idx] + btv[t];
}

// ---------------------------------------------------------------------------
__global__ __launch_bounds__(256) void k_cvt(const float* __restrict__ s,
                                             __hip_bfloat16* __restrict__ d, int n4){
  int i = blockIdx.x*256 + threadIdx.x;
  if (i >= n4) return;
  float4 v = reinterpret_cast<const float4*>(s)[i];
  union { __hip_bfloat16 h[4]; ushort4 u; } p;
  p.h[0] = __float2bfloat16(v.x); p.h[1] = __float2bfloat16(v.y);
  p.h[2] = __float2bfloat16(v.z); p.h[3] = __float2bfloat16(v.w);
  reinterpret_cast<ushort4*>(d)[i] = p.u;
}

// ---------------------------------------------------------------------------
// Weight prepack: Wp[wset][us(32)][row(64)][k(1024)] bf16
// ---------------------------------------------------------------------------
__global__ __launch_bounds__(256) void k_pack(
    const float* __restrict__ Whh_f, const float* __restrict__ Wih_f,
    const float* __restrict__ Whh_b, const float* __restrict__ Wih_b,
    __hip_bfloat16* __restrict__ Wp)
{
  int idx = blockIdx.x*256 + threadIdx.x;   // 1,048,576 quads
  int k4  = idx & 255;
  int row = (idx >> 8) & 63;
  int us  = (idx >> 14) & 31;
  int ws  = idx >> 19;
  int g = row >> 4, uu = row & 15;
  int srow = g*512 + us*16 + uu;
  int k = k4*4;
  const float* src;
  if (ws == 0) src = (k < 512) ? Whh_f : Wih_f;
  else         src = (k < 512) ? Whh_b : Wih_b;
  float4 v = *reinterpret_cast<const float4*>(src + (size_t)srow*512 + (k & 511));
  union { __hip_bfloat16 h[4]; ushort4 u; } p;
  p.h[0] = __float2bfloat16(v.x); p.h[1] = __float2bfloat16(v.y);
  p.h[2] = __float2bfloat16(v.z); p.h[3] = __float2bfloat16(v.w);
  *reinterpret_cast<ushort4*>(Wp + (size_t)idx*4) = p.u;
}

// ---------------------------------------------------------------------------
// Persistent 4-pass LSTM. 256 blocks x 512 threads, 1 block/CU (128 KiB LDS).
// grp = bid&7 (XCD-pinned: pp = grp>>2 weight set, bq = grp&3 batch pair);
// us = bid>>3. All cross-block traffic INTRA-XCD.
// SYNC (R16): per-block slot on its OWN 256-B cacheline (stride 64 ints) —
// eliminates the 32-writer/32-poller single-line ping-pong that R13-R15
// evidence isolated as the ~16 us/step floor. Posts = plain relaxed stores;
// wave-0 poll = 32 lanes reading 32 independent lines; buffer_inv sc0
// (L1-only) before release barrier (proven R13/R14).
// ---------------------------------------------------------------------------
__global__ __launch_bounds__(512) void k_persist(
    const __hip_bfloat16* __restrict__ Wp,
    const float* __restrict__ bih_f, const float* __restrict__ bhh_f,
    const float* __restrict__ bih_b, const float* __restrict__ bhh_b,
    const __hip_bfloat16* __restrict__ svb, const float* __restrict__ Wt,
    const int* __restrict__ lens,
    __hip_bfloat16* __restrict__ H,
    float* __restrict__ pt_acc, int* __restrict__ flags)
{
  const int bid = blockIdx.x;
  const int grp = bid & 7;          // XCD-aligned group
  const int us  = bid >> 3;         // 0..31
  const int pp  = grp >> 2;         // weight set (one per XCD)
  const int bq  = grp & 3;          // batch pair (one per XCD)
  const int L0 = lens[bq*2], L1 = lens[bq*2+1];
  const int kmax = (L0 > L1) ? L0 : L1;   // group-uniform step bound

  const float* b1 = pp ? bih_b : bih_f;
  const float* b2 = pp ? bhh_b : bhh_f;

  const int t = threadIdx.x, lane = t & 63, wv = t >> 6;
  const int c15 = lane & 15, qq = lane >> 4;
  const int ph = wv >> 2;           // pass half
  const int mq = wv & 3;            // row quarter
  const int pass = pp ? (ph ? 2 : 1) : (ph ? 3 : 0);
  const int b_loc = mq >> 1;
  const int b  = bq*2 + b_loc;
  const int L  = b_loc ? L1 : L0;
  const int rb0 = (mq & 1)*32;      // within-batch row base (+mt*16)

  __shared__ ushort Wlds[65536];    // 128 KiB: 64 rows x 2048 B, XOR-swizzled

  // ---- one-time W stage (swizzle byte-addr ^ (row&7)<<4) ----
  {
    const __hip_bfloat16* Wpb = Wp + (((size_t)pp*32 + us)*64)*1024;
    const int row = t >> 3, c8 = t & 7;
    const int swz = (row & 7) << 4;
    #pragma unroll
    for (int q=0; q<16; ++q){
      int4 v = *reinterpret_cast<const int4*>(Wpb + (size_t)row*1024 + c8*128 + q*8);
      *reinterpret_cast<int4*>((char*)Wlds + ((row*2048 + c8*256 + q*16) ^ swz)) = v;
    }
  }

  const int u = us*16 + c15;
  const float bsI = b1[u]        + b2[u];
  const float bsF = b1[512 + u]  + b2[512 + u];
  const float bsG = b1[1024 + u] + b2[1024 + u];
  const float bsO = b1[1536 + u] + b2[1536 + u];
  const int lswz = (c15 & 7) << 4;

  // sync slots: one per block, each on its OWN 256-B line (stride 64 ints)
  int* slots = flags + grp*2048;

  // projection: pidx = us*4 + mq in 0..127 per pass-half (bijective over grp)
  const int pidx = us*4 + mq;
  const int bp   = bq*2 + (pidx >> 6);
  const int rp   = pidx & 63;
  const int Lp   = (pidx >> 6) ? L1 : L0;
  const int off_wtp = (pass==0 || pass==2) ? 512 : 0;

  float creg[2][4];
  #pragma unroll
  for (int mt=0; mt<2; ++mt)
    #pragma unroll
    for (int e=0; e<4; ++e) creg[mt][e] = 0.f;

  __syncthreads();                  // Wlds ready

  for (int k=0; k<kmax; ++k){
    const int cur = k & 1;

    bool act_t[2];
    #pragma unroll
    for (int mt=0; mt<2; ++mt){
      const int rbase = rb0 + mt*16;
      act_t[mt] = (pass < 2) ? (rbase < L - k)
                             : (rbase + 15 >= k && rbase < L);
    }

    if (act_t[0] || act_t[1]){
      const __hip_bfloat16* hp[2];
      const __hip_bfloat16* xp[2];
      #pragma unroll
      for (int mt=0; mt<2; ++mt){
        const int r = rb0 + mt*16 + c15;
        int i, j; bool a_;
        posmap(pass, r, k, L, i, j, a_);
        hp[mt] = H + (((size_t)cur*4 + pass)*512 + b*64 + r)*512;
        xp[mt] = svb + ((size_t)b*TRIc + tri_idx(i, j))*512;
      }

      f32x4 acc[2][4];
      #pragma unroll
      for (int mt=0; mt<2; ++mt)
        #pragma unroll
        for (int g=0; g<4; ++g) acc[mt][g] = f32x4{0.f,0.f,0.f,0.f};

      #pragma unroll 4
      for (int c=0; c<16; ++c){
        bf16x8 a[2][2];               // [kk][mt]
        const int o = (c & 7)*64 + qq*8;
        #pragma unroll
        for (int mt=0; mt<2; ++mt){
          const __hip_bfloat16* p = (c < 8) ? hp[mt] : xp[mt];
          a[0][mt] = *reinterpret_cast<const bf16x8*>(p + o);
          a[1][mt] = *reinterpret_cast<const bf16x8*>(p + o + 32);
        }
        #pragma unroll
        for (int kk=0; kk<2; ++kk){
          #pragma unroll
          for (int g=0; g<4; ++g){
            const int addr = (((g*16 + c15)*2048) + (c*2 + kk)*64 + qq*16) ^ lswz;
            bf16x8 bf = *reinterpret_cast<const bf16x8*>((const char*)Wlds + addr);
            acc[0][g] = __builtin_amdgcn_mfma_f32_16x16x32_bf16(a[kk][0], bf, acc[0][g], 0,0,0);
            acc[1][g] = __builtin_amdgcn_mfma_f32_16x16x32_bf16(a[kk][1], bf, acc[1][g], 0,0,0);
          }
        }
      }

      // cell epilogue: D row = rb0 + mt*16 + qq*4 + e, col = c15
      #pragma unroll
      for (int mt=0; mt<2; ++mt){
        #pragma unroll
        for (int e=0; e<4; ++e){
          const int r = rb0 + mt*16 + qq*4 + e;
          int i, j; bool act;
          posmap(pass, r, k, L, i, j, act);
          if (act){
            float gi = acc[mt][0][e] + bsI;
            float gf = acc[mt][1][e] + bsF;
            float gg = acc[mt][2][e] + bsG;
            float go = acc[mt][3][e] + bsO;
            float ii = 1.f/(1.f + expf(-gi));
            float ff = 1.f/(1.f + expf(-gf));
            float gt = tanhf(gg);
            float oo = 1.f/(1.f + expf(-go));
            float cn = ff*creg[mt][e] + ii*gt;
            creg[mt][e] = cn;
            float hv = oo*tanhf(cn);
            H[(((size_t)(cur^1)*4 + pass)*512 + b*64 + r)*512 + u] = __float2bfloat16(hv);
          }
        }
      }
    }

    // ---- group sync (32 blocks, one XCD), line-contention-free:
    // barrier drains vmcnt -> plain-store post to OWN cacheline ->
    // wave0 polls 32 independent lines (one per lane) -> L1-only
    // invalidate -> release barrier.
    __syncthreads();
    if (wv == 0){
      if (lane == 0)
        __hip_atomic_store(&slots[us*64], k + 1, __ATOMIC_RELAXED,
                           __HIP_MEMORY_SCOPE_AGENT);
      for (;;){
        int v = 0x7fffffff;
        if (lane < 32)
          v = __hip_atomic_load(&slots[lane*64], __ATOMIC_RELAXED,
                                __HIP_MEMORY_SCOPE_AGENT);
        if (__all(v >= k + 1)) break;
        __builtin_amdgcn_s_sleep(1);
      }
      asm volatile("buffer_inv sc0\n\ts_waitcnt vmcnt(0)" ::: "memory");
    }
    __syncthreads();

    // ---- fused projection for step k (h complete in parity cur^1) ----
    if (k < Lp){
      int pi, pj; bool pact;
      posmap(pass, rp, k, Lp, pi, pj, pact);
      if (pact){
        const __hip_bfloat16* hrow =
            H + (((size_t)(cur^1)*4 + pass)*512 + bp*64 + rp)*512;
        bf16x8 hv8 = *reinterpret_cast<const bf16x8*>(hrow + lane*8);
        float hf[8];
        #pragma unroll
        for (int e=0; e<8; ++e) hf[e] = (float)hv8[e];
        float part[Tc];
        #pragma unroll
        for (int tt=0; tt<Tc; ++tt){
          const float* w = Wt + (size_t)tt*1024 + off_wtp + lane*8;
          float4 w0 = *reinterpret_cast<const float4*>(w);
          float4 w1 = *reinterpret_cast<const float4*>(w + 4);
          part[tt] = hf[0]*w0.x + hf[1]*w0.y + hf[2]*w0.z + hf[3]*w0.w
                   + hf[4]*w1.x + hf[5]*w1.y + hf[6]*w1.z + hf[7]*w1.w;
        }
        float* ptp = pt_acc + (size_t)(us & 3)*PTN;
        #pragma unroll
        for (int tt=0; tt<Tc; ++tt){
          float s = part[tt];
          s += __shfl_xor(s, 1);  s += __shfl_xor(s, 2);  s += __shfl_xor(s, 4);
          s += __shfl_xor(s, 8);  s += __shfl_xor(s, 16); s += __shfl_xor(s, 32);
          if (lane == tt)
            atomicAdd(&ptp[(((size_t)bp*Tc + tt)*Sc + pi)*Sc + pj], s);
        }
      }
    }
  }
}

// labeled[b,i,j] = logsumexp_t of masked pt
__global__ void k_lse(const float* __restrict__ pt_acc, const float* __restrict__ btv,
                      const int* __restrict__ lens, float* __restrict__ lab){
  const int idx = blockIdx.x*256 + threadIdx.x;  // 32768
  const int b = idx >> 12, ij = idx & 4095;
  const int i = ij >> 6, j = ij & 63;
  const int L = lens[b];
  float vs[Tc]; float m = -INFINITY;
  #pragma unroll
  for (int t=0;t<Tc;t++){ vs[t] = pt_val(pt_acc, btv, b, t, i, j, L); m = fmaxf(m, vs[t]); }
  float ssum = 0.f;
  #pragma unroll
  for (int t=0;t<Tc;t++) ssum += expf(vs[t]-m);
  lab[idx] = m + logf(ssum);
}

// matrix-tree slogdet per batch; no-pivot LU (leading minors positive), double.
__global__ __launch_bounds__(256) void k_logz(
    const float* __restrict__ lab, const int* __restrict__ lens,
    float* __restrict__ out)
{
  __shared__ double Md[64][65];
  __shared__ double part[4][64];
  __shared__ double rootv[64];
  const int b = blockIdx.x;
  const int L = lens[b];
  const int tid = threadIdx.x;
  const int c  = tid & 63;
  const int rg = tid >> 6;

  for (int r = rg; r < 64; r += 4){
    float lv = lab[((size_t)b*Sc + r)*Sc + c];
    double a;
    if (r == c) a = 0.0;
    else { a = 1e-5; if (r < L && c < L) a += exp((double)lv); }
    Md[r][c] = a;
  }
  if (rg == 0) rootv[c] = (c < L) ? exp((double)lab[((size_t)b*Sc + c)*Sc + c]) : 0.0;
  __syncthreads();
  {
    double ps = 0.0;
    for (int r = rg; r < 64; r += 4) ps += Md[r][c];
    part[rg][c] = ps;
  }
  __syncthreads();
  const double cs = part[0][c] + part[1][c] + part[2][c] + part[3][c];
  for (int r = rg; r < 64; r += 4){
    double v;
    if (r == 0) v = rootv[c];
    else { v = -Md[r][c]; if (r == c) v += cs + ((c >= L) ? 1.0 : 0.0); }
    Md[r][c] = v;
  }
  __syncthreads();

  double logdet = 0.0;
  for (int p = 0; p < 64; ++p){
    const double diag = Md[p][p];
    logdet += log(fabs(diag));
    if (c > p){
      const double inv = 1.0/diag;
      const double mpc = Md[p][c];
      for (int r = p + 1 + rg; r < 64; r += 4)
        Md[r][c] -= Md[r][p]*inv*mpc;
    }
    __syncthreads();
  }
  if (tid == 0) out[(size_t)Bc*Tc*65*65 + b] = (float)logdet;
}

// pe = _expand_matrix(masked pt)
__global__ void k_out(const float* __restrict__ pt_acc, const float* __restrict__ btv,
                      const int* __restrict__ lens, float* __restrict__ out){
  const int idx = blockIdx.x*256 + threadIdx.x;
  if (idx >= Bc*Tc*65*65) return;
  const int cc = idx % 65; int tmp = idx / 65;
  const int rr = tmp % 65; tmp /= 65;
  const int t  = tmp % Tc; const int b = tmp / Tc;
  float v;
  if (rr == cc) v = 0.f;
  else if (cc == 0) v = NEGF;
  else {
    const int i = (rr == 0) ? (cc-1) : (rr-1);
    v = pt_val(pt_acc, btv, b, t, i, cc-1, lens[b]);
  }
  out[idx] = v;
}

__global__ void k_zero_out(float* out, int n){
  int i = blockIdx.x*256 + threadIdx.x;
  if (i < n) out[i] = 0.f;
}

// ---------------------------------------------------------------------------
extern "C" void kernel_launch(void* const* d_in, const int* in_sizes, int n_in,
                              void* d_out, int out_size, void* d_ws, size_t ws_size,
                              hipStream_t stream)
{
  (void)in_sizes; (void)n_in;
  const int*   lens  = (const int*)  d_in[2];
  const float* sv    = (const float*)d_in[3];
  const float* Wih_f = (const float*)d_in[5];
  const float* Whh_f = (const float*)d_in[6];
  const float* bih_f = (const float*)d_in[7];
  const float* bhh_f = (const float*)d_in[8];
  const float* Wih_b = (const float*)d_in[9];
  const float* Whh_b = (const float*)d_in[10];
  const float* bih_b = (const float*)d_in[11];
  const float* bhh_b = (const float*)d_in[12];
  const float* Wt    = (const float*)d_in[13];
  const float* btv   = (const float*)d_in[14];

  const size_t SVB  = (size_t)Bc*TRIc*Hc*2;       // 17.0 MB bf16
  const size_t WPB  = (size_t)2*32*64*1024*2;     // 8.39 MB bf16
  const size_t PT4  = (size_t)4*PTN*4;            // 8.92 MB (4 parts)
  const size_t HB   = (size_t)2*4*512*512*2;      // 4.19 MB bf16
  const size_t LAB  = (size_t)Bc*Sc*Sc*4;         // 131 KB
  const size_t FLG  = (size_t)8*2048*4;           // 64 KB: 8 grp x 32 slots x 256B
  const size_t NEED = SVB + WPB + PT4 + HB + LAB + FLG + 8192;

  if (ws_size < NEED) {
    k_zero_out<<<dim3((out_size+255)/256), 256, 0, stream>>>((float*)d_out, out_size);
    return;
  }

  char* base = (char*)d_ws;
  size_t off = 0;
  auto take = [&](size_t bytes)->char*{
    char* r = base + off; off += (bytes + 255) & ~(size_t)255; return r; };

  __hip_bfloat16* svb = (__hip_bfloat16*)take(SVB);
  __hip_bfloat16* Wp  = (__hip_bfloat16*)take(WPB);
  float* pt_acc = (float*)take(PT4);
  __hip_bfloat16* H = (__hip_bfloat16*)take(HB);
  float* lab = (float*)take(LAB);
  int*   flags = (int*)take(FLG);

  // zero pt parts + H + lab + flags (contiguous takes)
  (void)hipMemsetAsync(pt_acc, 0, PT4 + HB + LAB + FLG, stream);

  k_cvt <<<dim3(8320), 256, 0, stream>>>(sv, svb, 2129920);
  k_pack<<<dim3(4096), 256, 0, stream>>>(Whh_f, Wih_f, Whh_b, Wih_b, Wp);

  k_persist<<<dim3(256), 512, 0, stream>>>(Wp, bih_f, bhh_f, bih_b, bhh_b,
                                           svb, Wt, lens, H, pt_acc, flags);

  k_lse <<<dim3(128), 256, 0, stream>>>(pt_acc, btv, lens, lab);
  k_logz<<<dim3(Bc), 256, 0, stream>>>(lab, lens, (float*)d_out);
  k_out <<<dim3((Bc*Tc*65*65 + 255)/256), 256, 0, stream>>>(pt_acc, btv, lens, (float*)d_out);
}